// Round 4
// baseline (239.568 us; speedup 1.0000x reference)
//
#include <hip/hip_runtime.h>

// DecoderLSTM: B=4096, T=128 (127 steps), H=128, 4H=512, V=30, E=256.
// R6: transposed MFMA (gates in M, batch rows in N). 256 blocks x 768 thr
// (12 waves = 3/SIMD, balanced).
//  Waves 0-7 (step t): acc[T] init = Xproj float4 bit-cast (no transpose movs,
//    gate g == C-reg r); gates += W_hh-frag (A) x h-frag (B) over 16 MFMA;
//    merged-rcp pointwise (5 exp2 + 3 rcp per element); h(t+1) -> LDS.
//    One token read + one load base per lane (lane owns ONE batch row).
//  Waves 8-11 (step t>=1, rotating on (t-1)&3): logits = W_lin-frag x h-frag
//    (vocab in M) -> softmax fully in-register (2x shfl_xor per reduction),
//    no logits LDS buffer. CE from LDS-staged tok/mask.
// One barrier/step. Last block publishes out = loss/mask via atomic counter.

typedef __bf16 bf16x8 __attribute__((ext_vector_type(8)));
typedef float  f32x4  __attribute__((ext_vector_type(4)));

namespace {
constexpr int Bn = 4096, Tn = 128, Vn = 30, En = 256, Hn = 128, Gn = 512;
constexpr int WS_LOSS  = 0;
constexpr int WS_MASK  = 1;
constexpr int WS_CNT   = 2;
constexpr int WS_XPROJ = 16;                  // 30*512 fp32, layout [v][k][g]
constexpr int WS_WF_F  = WS_XPROJ + Vn * Gn;  // 65536 bf16 Whh A-frags + 4096 bf16 Wlin A-frags
}

__device__ __forceinline__ float fexp2(float x) { return __builtin_amdgcn_exp2f(x); }
__device__ __forceinline__ float frcp(float x)  { return __builtin_amdgcn_rcpf(x); }

// ---- setup, 94 blocks x 256 (zeroes loss/mask/cnt)
__global__ void k_setup(const float* __restrict__ emb, const float* __restrict__ W_ih,
                        const float* __restrict__ b_ih, const float* __restrict__ b_hh,
                        const float* __restrict__ W_hh, const float* __restrict__ W_lin,
                        float* __restrict__ ws) {
  const int bid = blockIdx.x, tid = threadIdx.x;
  if (bid < 60) {
    __shared__ __align__(16) float es[En];
    int v = bid >> 1;
    int j = ((bid & 1) << 8) + tid;   // j = g*128 + k
    es[tid] = emb[v * En + tid];
    __syncthreads();
    float a = b_ih[j] + b_hh[j];
    const float* wr = W_ih + j * En;
#pragma unroll 4
    for (int e = 0; e < En; e += 4) {
      float4 w = *(const float4*)(wr + e);
      float4 x = *(const float4*)(es + e);
      a += x.x * w.x + x.y * w.y + x.z * w.z + x.w * w.w;
    }
    ws[WS_XPROJ + v * Gn + (j & 127) * 4 + (j >> 7)] = a;
  } else if (bid < 92) {
    // W_hh A-fragments (transposed MFMA: A row s = gate-col within tile).
    // fid = ((w*4 + T)*4 + kt)*64 + l ; n(s) = (s&3)*128 + w*16 + T*4 + (s>>2)
    int fid = (bid - 60) * 256 + tid;  // 0..8191
    int l = fid & 63, kt = (fid >> 6) & 3, T = (fid >> 8) & 3, w = fid >> 10;
    int n  = (l & 3) * 128 + w * 16 + T * 4 + ((l >> 2) & 3);
    int k0 = kt * 32 + (l >> 4) * 8;
    const float* src = W_hh + n * Hn + k0;
    union { __bf16 h[8]; uint4 u; } pk;
#pragma unroll
    for (int j = 0; j < 8; ++j) pk.h[j] = (__bf16)src[j];
    __bf16* wf = (__bf16*)(ws + WS_WF_F);
    *(uint4*)(wf + fid * 8) = pk.u;
  } else {
    // W_lin A-fragments: A row s -> vocab = T*16 + s ; fid = (T*4+kt)*64 + l
    int fid = (bid - 92) * 256 + tid;  // 0..511
    if (fid < 3) ws[fid] = 0.f;        // WS_LOSS, WS_MASK, WS_CNT
    int l = fid & 63, kt = (fid >> 6) & 3, T = fid >> 8;
    int vocab = T * 16 + (l & 15);
    int k0 = kt * 32 + (l >> 4) * 8;
    union { __bf16 h[8]; uint4 u; } pk;
#pragma unroll
    for (int j = 0; j < 8; ++j)
      pk.h[j] = (vocab < Vn) ? (__bf16)W_lin[vocab * Hn + k0 + j] : (__bf16)0.f;
    __bf16* wf = (__bf16*)(ws + WS_WF_F);
    *(uint4*)(wf + 65536 + fid * 8) = pk.u;
  }
}

// ---- main: 256 blocks x 768 threads (12 waves), 16 batch rows/block
__global__ __launch_bounds__(768, 3) void k_main(
    const int* __restrict__ inpt, const float* __restrict__ h0,
    const float* __restrict__ c0, const float* __restrict__ maskY,
    const float* __restrict__ b_lin, float* __restrict__ ws,
    float* __restrict__ out) {
  __shared__ __align__(16) __bf16 hbuf[2][16][136];  // 8.7 KB
  __shared__ int   tokL[16 * 129];                   // pad 129
  __shared__ float maskL[16 * 132];                  // pad 132

  const float4* X4 = (const float4*)(ws + WS_XPROJ); // [v*128 + k] -> (i,f,g,o)
  const __bf16* wf  = (const __bf16*)(ws + WS_WF_F);
  const __bf16* wlf = wf + 65536;

  const int tid = threadIdx.x;
  const int w = tid >> 6, l = tid & 63, quad = l >> 4, lc = l & 15;
  const int row0 = blockIdx.x * 16;

  // staging (all 12 waves)
  for (int idx = tid; idx < 16 * Tn; idx += 768) {
    int r = idx >> 7, t = idx & 127;
    tokL[r * 129 + t]  = inpt[(row0 + r) * Tn + t];
    maskL[r * 132 + t] = maskY[(row0 + r) * Tn + t];
  }
  for (int idx = tid; idx < 16 * Hn; idx += 768) {
    int r = idx >> 7, k = idx & 127;
    hbuf[0][r][k] = (__bf16)h0[(row0 + r) * Hn + k];
  }

  // weight fragments: branch-exclusive union (cores: W_hh[4][4]; sm: W_lin[2][4])
  bf16x8 wreg[4][4];
  float  creg[4];
  float  blin[2][4];
  float  mloc = 0.f, ce_acc = 0.f;

  if (w < 8) {
#pragma unroll
    for (int T = 0; T < 4; ++T)
#pragma unroll
      for (int kt = 0; kt < 4; ++kt)
        wreg[T][kt] = __builtin_bit_cast(
            bf16x8, *(const uint4*)(wf + (((w * 4 + T) * 4 + kt) * 64 + l) * 8));
#pragma unroll
    for (int T = 0; T < 4; ++T)
      creg[T] = c0[(row0 + lc) * Hn + w * 16 + T * 4 + quad];
    if (w == 7) {  // block-local mask sum (ref divides by full mask sum)
      float s = 0.f;
      const float4* m4 = (const float4*)(maskY + row0 * Tn);
#pragma unroll
      for (int i = 0; i < 8; ++i) s += m4[l + i * 64].x + m4[l + i * 64].y +
                                       m4[l + i * 64].z + m4[l + i * 64].w;
      mloc = s;
    }
  } else {
#pragma unroll
    for (int T = 0; T < 2; ++T)
#pragma unroll
      for (int kt = 0; kt < 4; ++kt)
        wreg[T][kt] = __builtin_bit_cast(
            bf16x8, *(const uint4*)(wlf + ((T * 4 + kt) * 64 + l) * 8));
#pragma unroll
    for (int T = 0; T < 2; ++T)
#pragma unroll
      for (int r = 0; r < 4; ++r) {
        int vo = T * 16 + quad * 4 + r;
        blin[T][r] = (vo < Vn) ? b_lin[vo] : -1e30f;
      }
  }
  __syncthreads();

  const int toff = lc * 129;            // token row base
  const int moff = lc * 132;            // mask row base
  const int aoff = lc * 136 + quad * 8; // h-frag (B operand) base
  const int woff = lc * 136 + w * 16 + quad; // h-write base (cores)

  // Xproj preload for t=0 (cores): one base, immediate offsets
  float4 xv[4];
  if (w < 8) {
    int tok = tokL[toff];
    const float4* xb = X4 + tok * 128 + w * 16 + quad;
#pragma unroll
    for (int T = 0; T < 4; ++T) xv[T] = xb[T * 4];
  }

  for (int t = 0; t < Tn; ++t) {  // cores act t<127, softmax waves t>=1
    const __bf16* hc = &hbuf[t & 1][0][0];
    __bf16*       hn = &hbuf[(t & 1) ^ 1][0][0];

    if (w < 8) {
      if (t < Tn - 1) {
        bf16x8 af[4];
#pragma unroll
        for (int kt = 0; kt < 4; ++kt)
          af[kt] = __builtin_bit_cast(bf16x8, *(const uint4*)(hc + aoff + kt * 32));
        int tok = tokL[toff + t + 1];

        f32x4 acc[4];
#pragma unroll
        for (int T = 0; T < 4; ++T) acc[T] = __builtin_bit_cast(f32x4, xv[T]);
#pragma unroll
        for (int T = 0; T < 4; ++T)
#pragma unroll
          for (int kt = 0; kt < 4; ++kt)
            acc[T] = __builtin_amdgcn_mfma_f32_16x16x32_bf16(wreg[T][kt], af[kt], acc[T], 0, 0, 0);

        // prefetch Xproj for t+1 (drains at the barrier)
        float4 xn[4];
        const float4* xb = X4 + tok * 128 + w * 16 + quad;
#pragma unroll
        for (int T = 0; T < 4; ++T) xn[T] = xb[T * 4];

#pragma unroll
        for (int T = 0; T < 4; ++T) {
          float iv = acc[T][0], fv = acc[T][1], gv = acc[T][2], ov = acc[T][3];
          float ef = fexp2(fv * -1.44269504f);
          float ei = fexp2(iv * -1.44269504f);
          float eo = fexp2(ov * -1.44269504f);
          float eg = fexp2(fminf(gv, 16.f) * 2.88539008f);
          float sf = frcp(1.f + ef);                                // sigmoid(f)
          float itg = (eg - 1.f) * frcp((1.f + ei) * (1.f + eg));   // sig(i)*tanh(g)
          float c2 = sf * creg[T] + itg;
          float ec = fexp2(fminf(c2, 16.f) * 2.88539008f);
          float h2 = (ec - 1.f) * frcp((1.f + eo) * (1.f + ec));    // sig(o)*tanh(c2)
          creg[T] = c2;
          xv[T] = xn[T];
          hn[woff + T * 4] = (__bf16)h2;
        }
      }
    } else if (t >= 1 && (w - 8) == ((t - 1) & 3)) {
      // logits of h(t) = CE for ref-step t-1; targets tok[:,t], mask[:,t-1]
      bf16x8 af[4];
#pragma unroll
      for (int kt = 0; kt < 4; ++kt)
        af[kt] = __builtin_bit_cast(bf16x8, *(const uint4*)(hc + aoff + kt * 32));
      f32x4 lacc[2];
#pragma unroll
      for (int T = 0; T < 2; ++T)
#pragma unroll
        for (int r = 0; r < 4; ++r) lacc[T][r] = blin[T][r];
#pragma unroll
      for (int T = 0; T < 2; ++T)
#pragma unroll
        for (int kt = 0; kt < 4; ++kt)
          lacc[T] = __builtin_amdgcn_mfma_f32_16x16x32_bf16(wreg[T][kt], af[kt], lacc[T], 0, 0, 0);

      // in-register softmax: lane holds 8 vocab vals of row lc; reduce over quads
      float m = lacc[0][0];
#pragma unroll
      for (int T = 0; T < 2; ++T)
#pragma unroll
        for (int r = 0; r < 4; ++r) m = fmaxf(m, lacc[T][r]);
      m = fmaxf(m, __shfl_xor(m, 16));
      m = fmaxf(m, __shfl_xor(m, 32));
      float e = 0.f;
#pragma unroll
      for (int T = 0; T < 2; ++T)
#pragma unroll
        for (int r = 0; r < 4; ++r) e += fexp2((lacc[T][r] - m) * 1.44269504f);
      e += __shfl_xor(e, 16);
      e += __shfl_xor(e, 32);
      int y = tokL[toff + t];
      float cand = 0.f;
#pragma unroll
      for (int T = 0; T < 2; ++T)
#pragma unroll
        for (int r = 0; r < 4; ++r)
          cand = ((T * 16 + quad * 4 + r) == y) ? lacc[T][r] : cand;
      cand += __shfl_xor(cand, 16);
      cand += __shfl_xor(cand, 32);
      if (quad == 0) {
        float ce = (m + __logf(e)) - cand;
        ce_acc += ce * maskL[moff + t - 1];
      }
    }
    __syncthreads();  // the only barrier: h(t+1) published
  }

  // final reductions
  if (w == 7) {
#pragma unroll
    for (int off = 32; off > 0; off >>= 1) mloc += __shfl_down(mloc, off);
    if (l == 0) atomicAdd(ws + WS_MASK, mloc);
  }
  if (w >= 8) {
#pragma unroll
    for (int off = 32; off > 0; off >>= 1) ce_acc += __shfl_down(ce_acc, off);
    if (l == 0) atomicAdd(ws + WS_LOSS, ce_acc);
  }
  __syncthreads();  // all block-local atomics drained (vmcnt at barrier)
  if (tid == 0) {
    __threadfence();
    unsigned old = atomicAdd((unsigned*)(ws + WS_CNT), 1u);
    if (old == 255) {  // last block: publish result
      float lv = atomicAdd(ws + WS_LOSS, 0.f);
      float mv = atomicAdd(ws + WS_MASK, 0.f);
      out[0] = lv / mv;
    }
  }
}

extern "C" void kernel_launch(void* const* d_in, const int* in_sizes, int n_in,
                              void* d_out, int out_size, void* d_ws, size_t ws_size,
                              hipStream_t stream) {
  const int*   inpt  = (const int*)  d_in[0];
  const float* h0    = (const float*)d_in[1];
  const float* c0    = (const float*)d_in[2];
  const float* maskY = (const float*)d_in[3];
  // d_in[4] = beta (unused)
  const float* emb   = (const float*)d_in[5];
  const float* W_ih  = (const float*)d_in[6];
  const float* b_ih  = (const float*)d_in[7];
  const float* W_hh  = (const float*)d_in[8];
  const float* b_hh  = (const float*)d_in[9];
  const float* W_lin = (const float*)d_in[10];
  const float* b_lin = (const float*)d_in[11];
  float* ws  = (float*)d_ws;
  float* out = (float*)d_out;

  hipLaunchKernelGGL(k_setup, dim3(94),  dim3(256), 0, stream,
                     emb, W_ih, b_ih, b_hh, W_hh, W_lin, ws);
  hipLaunchKernelGGL(k_main,  dim3(256), dim3(768), 0, stream,
                     inpt, h0, c0, maskY, b_lin, ws, out);
}

// Round 7
// 229.275 us; speedup vs baseline: 1.0449x; 1.0449x over previous
//
#include <hip/hip_runtime.h>

// DecoderLSTM: B=4096, T=128 (127 steps), H=128, 4H=512, V=30, E=256.
// R7 = R5 (best measured, 167.8us k_main) + relaxed per-step barrier.
// R5: wave-specialized, balanced pipeline. 256 blocks x 576 thr (9 waves).
//  Waves 0-7 (step t): gates = Xproj[tok] (prefetched, acc-init) + h(t) @
//    W_hh^T (16 MFMA, W-frags in regs) -> pointwise cell -> h(t+1) to LDS.
//  Wave 8 (step t>=1): logits of h(t) (8 MFMA, W_lin frags in SAME reg array
//    as cores' W_hh - branch-exclusive union), softmax via LDS-transpose
//    (only 2 shfl rounds), CE from LDS-staged tok/mask.
// R7 change: the in-loop __syncthreads() forced s_waitcnt vmcnt(0) before
//  s_barrier (HIP compiler semantics), draining the Xproj L2-gather every
//  step. Replaced with s_waitcnt lgkmcnt(0) + raw s_barrier (LDS h-writes
//  are all the barrier must order; no global communication in-loop), so
//  prefetch loads stay in flight across the barrier (T4 mechanism).
// Last block computes out = loss/mask via atomic completion counter.

typedef __bf16 bf16x8 __attribute__((ext_vector_type(8)));
typedef float  f32x4  __attribute__((ext_vector_type(4)));

namespace {
constexpr int Bn = 4096, Tn = 128, Vn = 30, En = 256, Hn = 128, Gn = 512;
constexpr int WS_LOSS  = 0;
constexpr int WS_MASK  = 1;
constexpr int WS_CNT   = 2;
constexpr int WS_XPROJ = 16;                  // 30*512 fp32, layout [v][k][g]
constexpr int WS_WF_F  = WS_XPROJ + Vn * Gn;  // 65536 bf16 Whh-frags + 4096 bf16 Wlin-frags
}

__device__ __forceinline__ float fexp2(float x) { return __builtin_amdgcn_exp2f(x); }
__device__ __forceinline__ float frcp(float x)  { return __builtin_amdgcn_rcpf(x); }
__device__ __forceinline__ float sigf(float x)  { return frcp(1.f + fexp2(x * -1.44269504f)); }
__device__ __forceinline__ float tanh_(float x) { return 1.f - 2.f * frcp(fexp2(x * 2.88539008f) + 1.f); }

// relaxed barrier: order LDS ops only; global loads stay in flight across it
__device__ __forceinline__ void lds_barrier() {
  __builtin_amdgcn_sched_barrier(0);
  asm volatile("s_waitcnt lgkmcnt(0)" ::: "memory");
  __builtin_amdgcn_s_barrier();
  __builtin_amdgcn_sched_barrier(0);
}

// ---- setup, 94 blocks x 256 (R4 layout; zeroes loss/mask/cnt)
__global__ void k_setup(const float* __restrict__ emb, const float* __restrict__ W_ih,
                        const float* __restrict__ b_ih, const float* __restrict__ b_hh,
                        const float* __restrict__ W_hh, const float* __restrict__ W_lin,
                        float* __restrict__ ws) {
  const int bid = blockIdx.x, tid = threadIdx.x;
  if (bid < 60) {
    __shared__ __align__(16) float es[En];
    int v = bid >> 1;
    int j = ((bid & 1) << 8) + tid;   // j = g*128 + k
    es[tid] = emb[v * En + tid];
    __syncthreads();
    float a = b_ih[j] + b_hh[j];
    const float* wr = W_ih + j * En;
#pragma unroll 4
    for (int e = 0; e < En; e += 4) {
      float4 w = *(const float4*)(wr + e);
      float4 x = *(const float4*)(es + e);
      a += x.x * w.x + x.y * w.y + x.z * w.z + x.w * w.w;
    }
    ws[WS_XPROJ + v * Gn + (j & 127) * 4 + (j >> 7)] = a;
  } else if (bid < 92) {
    int fid = (bid - 60) * 256 + tid;  // 0..8191
    int l = fid & 63, kt = (fid >> 6) & 3, g = (fid >> 8) & 3, w = fid >> 10;
    int n  = (g * 8 + w) * 16 + (l & 15);
    int k0 = kt * 32 + (l >> 4) * 8;
    const float* src = W_hh + n * Hn + k0;
    union { __bf16 h[8]; uint4 u; } pk;
#pragma unroll
    for (int j = 0; j < 8; ++j) pk.h[j] = (__bf16)src[j];
    __bf16* wf = (__bf16*)(ws + WS_WF_F);
    *(uint4*)(wf + fid * 8) = pk.u;
  } else {
    int fid = (bid - 92) * 256 + tid;  // 0..511
    if (fid < 3) ws[fid] = 0.f;        // WS_LOSS, WS_MASK, WS_CNT
    int l = fid & 63, kt = (fid >> 6) & 3, n = fid >> 8;
    int col = n * 16 + (l & 15);
    int k0  = kt * 32 + (l >> 4) * 8;
    union { __bf16 h[8]; uint4 u; } pk;
#pragma unroll
    for (int j = 0; j < 8; ++j)
      pk.h[j] = (col < Vn) ? (__bf16)W_lin[col * Hn + k0 + j] : (__bf16)0.f;
    __bf16* wf = (__bf16*)(ws + WS_WF_F);
    *(uint4*)(wf + 65536 + fid * 8) = pk.u;
  }
}

// ---- main: 256 blocks x 576 threads (9 waves), 16 batch rows/block
__global__ __launch_bounds__(576, 1) void k_main(
    const int* __restrict__ inpt, const float* __restrict__ h0,
    const float* __restrict__ c0, const float* __restrict__ maskY,
    const float* __restrict__ b_lin, float* __restrict__ ws,
    float* __restrict__ out) {
  __shared__ __align__(16) __bf16 hbuf[2][16][136];  // 8.7 KB
  __shared__ int   tokL[16 * 129];                   // pad 129: conflict-free col reads
  __shared__ float maskL[16 * 132];                  // pad 132
  __shared__ __align__(16) float logits[16 * 36];    // pad 36: aligned b128 transpose reads
  __shared__ float red[2];

  const float4* X4 = (const float4*)(ws + WS_XPROJ); // [v*128 + k] -> (i,f,g,o)
  const __bf16* wf = (const __bf16*)(ws + WS_WF_F);
  const __bf16* wlf = wf + 65536;

  const int tid = threadIdx.x;
  const int w = tid >> 6, l = tid & 63, quad = l >> 4, lc = l & 15;
  const int row0 = blockIdx.x * 16;
  const int kh = w * 16 + lc;

  // staging (all 9 waves)
  for (int idx = tid; idx < 16 * Tn; idx += 576) {
    int r = idx >> 7, t = idx & 127;
    tokL[r * 129 + t]  = inpt[(row0 + r) * Tn + t];
    maskL[r * 132 + t] = maskY[(row0 + r) * Tn + t];
  }
  for (int idx = tid; idx < 16 * Hn; idx += 576) {
    int r = idx >> 7, k = idx & 127;
    hbuf[0][r][k] = (__bf16)h0[(row0 + r) * Hn + k];
  }

  // weight fragments: branch-exclusive union (cores: W_hh[4][4]; wave8: W_lin[2][4])
  bf16x8 wreg[4][4];
  float  creg[4];
  float  bias0 = 0.f, bias1 = 0.f, mloc = 0.f;
  if (w < 8) {
#pragma unroll
    for (int g = 0; g < 4; ++g)
#pragma unroll
      for (int kt = 0; kt < 4; ++kt)
        wreg[g][kt] = __builtin_bit_cast(
            bf16x8, *(const uint4*)(wf + (((w * 4 + g) * 4 + kt) * 64 + l) * 8));
#pragma unroll
    for (int p = 0; p < 4; ++p)
      creg[p] = c0[(row0 + quad * 4 + p) * Hn + kh];
    if (w == 7) {  // block-local mask sum (all 128 cols — reference divides by full sum)
      float s = 0.f;
      const float4* m4 = (const float4*)(maskY + row0 * Tn);
#pragma unroll
      for (int i = 0; i < 8; ++i) s += m4[l + i * 64].x + m4[l + i * 64].y +
                                       m4[l + i * 64].z + m4[l + i * 64].w;
      mloc = s;
    }
  } else {
#pragma unroll
    for (int n = 0; n < 2; ++n)
#pragma unroll
      for (int kt = 0; kt < 4; ++kt)
        wreg[n][kt] = __builtin_bit_cast(
            bf16x8, *(const uint4*)(wlf + ((n * 4 + kt) * 64 + l) * 8));
    bias0 = b_lin[lc];
    bias1 = (lc < Vn - 16) ? b_lin[lc + 16] : -1e30f;
  }
  float ce_acc = 0.f;
  __syncthreads();

  // Xproj preload for t=0 (cores)
  float4 xv[4];
  if (w < 8) {
#pragma unroll
    for (int p = 0; p < 4; ++p)
      xv[p] = X4[tokL[(quad * 4 + p) * 129] * 128 + kh];
  }

  for (int t = 0; t < Tn; ++t) {  // 128 iterations; cores act t<127, wave8 t>=1
    const int par = t & 1;
    const __bf16* hc = &hbuf[par][0][0];
    __bf16*       hn = &hbuf[par ^ 1][0][0];

    if (w < 8) {
      if (t < Tn - 1) {
        bf16x8 af[4];
#pragma unroll
        for (int kt = 0; kt < 4; ++kt)
          af[kt] = __builtin_bit_cast(
              bf16x8, *(const uint4*)(hc + lc * 136 + kt * 32 + quad * 8));

        // next-step token indices (LDS, issued early)
        int tk[4];
#pragma unroll
        for (int p = 0; p < 4; ++p) tk[p] = tokL[(quad * 4 + p) * 129 + t + 1];

        f32x4 acc[4];
#pragma unroll
        for (int p = 0; p < 4; ++p) {
          acc[0][p] = xv[p].x; acc[1][p] = xv[p].y;
          acc[2][p] = xv[p].z; acc[3][p] = xv[p].w;
        }
#pragma unroll
        for (int g = 0; g < 4; ++g)
#pragma unroll
          for (int kt = 0; kt < 4; ++kt)
            acc[g] = __builtin_amdgcn_mfma_f32_16x16x32_bf16(af[kt], wreg[g][kt], acc[g], 0, 0, 0);

        // prefetch Xproj for t+1 (now survives across the relaxed barrier)
        float4 xn[4];
#pragma unroll
        for (int p = 0; p < 4; ++p) xn[p] = X4[tk[p] * 128 + kh];

#pragma unroll
        for (int p = 0; p < 4; ++p) {
          float c2 = sigf(acc[1][p]) * creg[p] + sigf(acc[0][p]) * tanh_(acc[2][p]);
          float h2 = sigf(acc[3][p]) * tanh_(c2);
          creg[p] = c2;
          hn[(quad * 4 + p) * 136 + kh] = (__bf16)h2;
          xv[p] = xn[p];
        }
      }
    } else if (t >= 1) {
      // logits of h(t) = CE for ref-step t-1; targets tok[:,t], mask[:,t-1]
      bf16x8 af[4];
#pragma unroll
      for (int kt = 0; kt < 4; ++kt)
        af[kt] = __builtin_bit_cast(
            bf16x8, *(const uint4*)(hc + lc * 136 + kt * 32 + quad * 8));
      f32x4 lacc[2] = {{bias0, bias0, bias0, bias0}, {bias1, bias1, bias1, bias1}};
#pragma unroll
      for (int kt = 0; kt < 4; ++kt) {
        lacc[0] = __builtin_amdgcn_mfma_f32_16x16x32_bf16(af[kt], wreg[0][kt], lacc[0], 0, 0, 0);
        lacc[1] = __builtin_amdgcn_mfma_f32_16x16x32_bf16(af[kt], wreg[1][kt], lacc[1], 0, 0, 0);
      }
      // C-layout -> LDS [row][v] (stride 36)
#pragma unroll
      for (int p = 0; p < 4; ++p) {
        logits[(quad * 4 + p) * 36 + lc]      = lacc[0][p];
        logits[(quad * 4 + p) * 36 + 16 + lc] = lacc[1][p];
      }
      // transpose-softmax: 4 lanes per row, 8 logits each, 2 shfl rounds
      int row = l >> 2, j = l & 3;
      float4 v0 = *(const float4*)(logits + row * 36 + j * 8);
      float4 v1 = *(const float4*)(logits + row * 36 + j * 8 + 4);
      float m = fmaxf(fmaxf(fmaxf(v0.x, v0.y), fmaxf(v0.z, v0.w)),
                      fmaxf(fmaxf(v1.x, v1.y), fmaxf(v1.z, v1.w)));
      m = fmaxf(m, __shfl_xor(m, 1));
      m = fmaxf(m, __shfl_xor(m, 2));
      float e = fexp2((v0.x - m) * 1.44269504f) + fexp2((v0.y - m) * 1.44269504f) +
                fexp2((v0.z - m) * 1.44269504f) + fexp2((v0.w - m) * 1.44269504f) +
                fexp2((v1.x - m) * 1.44269504f) + fexp2((v1.y - m) * 1.44269504f) +
                fexp2((v1.z - m) * 1.44269504f) + fexp2((v1.w - m) * 1.44269504f);
      e += __shfl_xor(e, 1);
      e += __shfl_xor(e, 2);
      if (j == 0) {
        int   y  = tokL[row * 129 + t];
        float ly = logits[row * 36 + y];
        float ce = (m + __logf(e)) - ly;
        ce_acc += ce * maskL[row * 132 + t - 1];
      }
    }
    lds_barrier();  // the only per-step barrier: LDS-ordered, vmcnt NOT drained
  }

  // final reductions: wave 7 mask partial -> LDS; wave 8 reduces CE + finishes
  if (w == 7) {
#pragma unroll
    for (int off = 32; off > 0; off >>= 1) mloc += __shfl_down(mloc, off);
    if (l == 0) red[0] = mloc;
  }
  __syncthreads();
  if (w == 8) {
#pragma unroll
    for (int off = 32; off > 0; off >>= 1) ce_acc += __shfl_down(ce_acc, off);
    if (l == 0) {
      atomicAdd(ws + WS_LOSS, ce_acc);
      atomicAdd(ws + WS_MASK, red[0]);
      __threadfence();
      unsigned old = atomicAdd((unsigned*)(ws + WS_CNT), 1u);
      if (old == 255) {  // last block: publish result
        float lv = atomicAdd(ws + WS_LOSS, 0.f);
        float mv = atomicAdd(ws + WS_MASK, 0.f);
        out[0] = lv / mv;
      }
    }
  }
}

extern "C" void kernel_launch(void* const* d_in, const int* in_sizes, int n_in,
                              void* d_out, int out_size, void* d_ws, size_t ws_size,
                              hipStream_t stream) {
  const int*   inpt  = (const int*)  d_in[0];
  const float* h0    = (const float*)d_in[1];
  const float* c0    = (const float*)d_in[2];
  const float* maskY = (const float*)d_in[3];
  // d_in[4] = beta (unused)
  const float* emb   = (const float*)d_in[5];
  const float* W_ih  = (const float*)d_in[6];
  const float* b_ih  = (const float*)d_in[7];
  const float* W_hh  = (const float*)d_in[8];
  const float* b_hh  = (const float*)d_in[9];
  const float* W_lin = (const float*)d_in[10];
  const float* b_lin = (const float*)d_in[11];
  float* ws  = (float*)d_ws;
  float* out = (float*)d_out;

  hipLaunchKernelGGL(k_setup, dim3(94),  dim3(256), 0, stream,
                     emb, W_ih, b_ih, b_hh, W_hh, W_lin, ws);
  hipLaunchKernelGGL(k_main,  dim3(256), dim3(576), 0, stream,
                     inpt, h0, c0, maskY, b_lin, ws, out);
}